// Round 8
// baseline (201.248 us; speedup 1.0000x reference)
//
#include <hip/hip_runtime.h>
#include <hip/hip_bf16.h>
#include <stdint.h>

#define B_SZ 2
#define S_LEN 2048
#define D_MODEL 2048
#define NH 32
#define NG 8
#define HGRP 4
#define DHEAD 64
#define KV_DIM 512       // NG*DHEAD
#define M_TOK 4096       // B_SZ*S_LEN
#define KVB2 128         // attention KV tile
#define QBLK 256
#define N_ITEMS2 768     // 12 slot-classes * 64 (b,head)

typedef __attribute__((ext_vector_type(8))) short bf16x8;
typedef __attribute__((ext_vector_type(4))) float f32x4;
typedef __attribute__((ext_vector_type(16))) float f32x16;

__device__ inline unsigned short f2bf(float x) {
    uint32_t u = __builtin_bit_cast(uint32_t, x);
    uint32_t r = (u + 0x7fffu + ((u >> 16) & 1u)) >> 16;
    return (unsigned short)r;
}

__device__ inline uint32_t cvtpk(float lo, float hi) {
    uint32_t r;
    asm("v_cvt_pk_bf16_f32 %0, %1, %2" : "=v"(r) : "v"(lo), "v"(hi));
    return r;
}

__device__ inline void plswap(uint32_t& a, uint32_t& b) {
    asm volatile("v_permlane32_swap_b32 %0, %1" : "+v"(a), "+v"(b));
}

__device__ inline float bf2f(unsigned short u) {
    uint32_t x = ((uint32_t)u) << 16;
    return __builtin_bit_cast(float, x);
}

__device__ inline void async_copy16(const void* g, void* l) {
    __builtin_amdgcn_global_load_lds(
        (const __attribute__((address_space(1))) void*)g,
        (__attribute__((address_space(3))) void*)l,
        16, 0, 0);
}

__device__ inline void gbar() {
    asm volatile("" ::: "memory");
    __builtin_amdgcn_s_barrier();
    asm volatile("" ::: "memory");
}
__device__ inline void lgkm0() {
    asm volatile("s_waitcnt lgkmcnt(0)" ::: "memory");
    __builtin_amdgcn_sched_barrier(0);
}

// ---------------- fused f32 -> bf16 convert (all 7 tensors) ----------------
__global__ __launch_bounds__(256) void cvt_all(const float* __restrict__ q,
                                               const float* __restrict__ k,
                                               const float* __restrict__ v,
                                               const float* __restrict__ wq,
                                               const float* __restrict__ wk,
                                               const float* __restrict__ wv,
                                               const float* __restrict__ wo,
                                               unsigned short* __restrict__ qb,
                                               unsigned short* __restrict__ kb,
                                               unsigned short* __restrict__ vb,
                                               unsigned short* __restrict__ wqb,
                                               unsigned short* __restrict__ wkvb,
                                               unsigned short* __restrict__ wob,
                                               unsigned int* __restrict__ cnt) {
    const int i = blockIdx.x * 256 + threadIdx.x;
    if (i == 0) *cnt = 0u;
    const float* src; unsigned short* dst; int j;
    if (i < 1048576)      { src = q;  dst = qb;  j = i; }
    else if (i < 2097152) { src = k;  dst = kb;  j = i - 1048576; }
    else if (i < 3145728) { src = v;  dst = vb;  j = i - 2097152; }
    else if (i < 3670016) { src = wq; dst = wqb; j = i - 3145728; }
    else if (i < 3801088) { src = wk; dst = wkvb; j = i - 3670016; }
    else if (i < 3932160) { src = wv; dst = wkvb + (size_t)KV_DIM * D_MODEL; j = i - 3801088; }
    else                  { src = wo; dst = wob; j = i - 3932160; }
    const float4* p = reinterpret_cast<const float4*>(src) + (size_t)j * 2;
    float4 a = p[0], b = p[1];
    union { unsigned short u[8]; uint4 v4; } r;
    r.u[0] = f2bf(a.x); r.u[1] = f2bf(a.y); r.u[2] = f2bf(a.z); r.u[3] = f2bf(a.w);
    r.u[4] = f2bf(b.x); r.u[5] = f2bf(b.y); r.u[6] = f2bf(b.z); r.u[7] = f2bf(b.w);
    reinterpret_cast<uint4*>(dst)[j] = r.v4;
}

#define SCALE_Q 0.1803368867f   // 0.125 * log2(e)
#define GK 2048

// ---------------- proj GEMM: 256x256 8-phase, N-stacked q|k|v ----------------
__global__ __launch_bounds__(512, 2) void gemm8p(const unsigned short* __restrict__ Aq,
                                                 const unsigned short* __restrict__ Ak,
                                                 const unsigned short* __restrict__ Av,
                                                 const unsigned short* __restrict__ Bq,
                                                 const unsigned short* __restrict__ Bkv,
                                                 unsigned short* __restrict__ out_q,
                                                 unsigned short* __restrict__ out_k,
                                                 unsigned short* __restrict__ out_v) {
    __shared__ __align__(16) char lds[131072];

    const int tid = threadIdx.x;
    const int lane = tid & 63;
    const int w = tid >> 6;
    const int wm = w >> 2, wn = w & 3;
    const int l15 = lane & 15, l4 = lane >> 4;

    int bid = blockIdx.x;
    bid = (bid & 7) * 24 + (bid >> 3);      // bijective XCD swizzle, 192 blocks
    const int mb = bid & 15, nb = bid >> 4;
    const int m0 = mb * 256;

    const unsigned short* Ap;
    const unsigned short* Bp;
    int mode = 0, n0q = 0;
    if (nb < 8) {
        Ap = Aq; Bp = Bq + (size_t)(nb * 256) * GK; mode = 0; n0q = nb * 256;
    } else if (nb < 10) {
        Ap = Ak; Bp = Bkv + (size_t)((nb - 8) * 256) * GK; mode = 1; n0q = (nb - 8) * 256;
    } else {
        Ap = Av; Bp = Bkv + (size_t)((nb - 10) * 256 + 512) * GK; mode = 2; n0q = (nb - 10) * 256;
    }

    const int srow = tid >> 3;
    const int gcol = (((tid & 7) * 16) ^ ((srow & 7) << 4)) >> 1;
    char* const myl = lds + tid * 16;

    auto stageA = [&](int tile, int half) {
        char* dst = myl + (tile & 1) * 32768 + half * 16384;
        const unsigned short* src = Ap + (size_t)(m0 + half * 128 + srow) * GK + tile * 64 + gcol;
        async_copy16(src, dst);
        async_copy16(src + (size_t)64 * GK, dst + 8192);
    };
    auto stageB = [&](int tile, int half) {
        char* dst = myl + 65536 + (tile & 1) * 32768 + half * 16384;
        const unsigned short* src = Bp + (size_t)(half * 128 + srow) * GK + tile * 64 + gcol;
        async_copy16(src, dst);
        async_copy16(src + (size_t)64 * GK, dst + 8192);
    };

    bf16x8 af[4][2], bf[4][2];
    auto loadA = [&](int buf, int mhalf) {
        const char* base = lds + buf * 32768;
#pragma unroll
        for (int mi = 0; mi < 4; ++mi) {
            const int r = wm * 128 + mhalf * 64 + mi * 16 + l15;
#pragma unroll
            for (int ks = 0; ks < 2; ++ks)
                af[mi][ks] = *reinterpret_cast<const bf16x8*>(
                    base + r * 128 + ((ks * 64 + l4 * 16) ^ ((r & 7) << 4)));
        }
    };
    auto loadB = [&](int buf, int nhalf) {
        const char* base = lds + 65536 + buf * 32768;
#pragma unroll
        for (int ni2 = 0; ni2 < 2; ++ni2) {
            const int ni = nhalf * 2 + ni2;
            const int r = wn * 64 + ni * 16 + l15;
#pragma unroll
            for (int ks = 0; ks < 2; ++ks)
                bf[ni][ks] = *reinterpret_cast<const bf16x8*>(
                    base + r * 128 + ((ks * 64 + l4 * 16) ^ ((r & 7) << 4)));
        }
    };

    f32x4 acc[8][4] = {};
    auto mfma16 = [&](int mq, int nq) {
        __builtin_amdgcn_s_setprio(1);
#pragma unroll
        for (int mi = 0; mi < 4; ++mi)
#pragma unroll
            for (int ni2 = 0; ni2 < 2; ++ni2)
#pragma unroll
                for (int ks = 0; ks < 2; ++ks)
                    acc[mq * 4 + mi][nq * 2 + ni2] = __builtin_amdgcn_mfma_f32_16x16x32_bf16(
                        af[mi][ks], bf[nq * 2 + ni2][ks], acc[mq * 4 + mi][nq * 2 + ni2], 0, 0, 0);
        __builtin_amdgcn_s_setprio(0);
    };

    stageA(0, 0); stageA(0, 1); stageB(0, 0); stageB(0, 1); stageB(1, 0); stageB(1, 1);
    asm volatile("s_waitcnt vmcnt(4)" ::: "memory");
    gbar();

    for (int i = 0; i < 16; ++i) {
        const int u = 2 * i;
        const bool nl = (i < 15);
        loadA(0, 0); loadB(0, 0); stageA(u + 1, 0);
        gbar(); lgkm0(); mfma16(0, 0); gbar();
        loadB(0, 1); stageA(u + 1, 1);
        gbar(); lgkm0(); mfma16(0, 1); gbar();
        loadA(0, 1); if (nl) stageB(u + 2, 0);
        gbar(); lgkm0(); mfma16(1, 0); gbar();
        if (nl) stageB(u + 2, 1);
        gbar(); mfma16(1, 1);
        if (nl) asm volatile("s_waitcnt vmcnt(4)" ::: "memory");
        else    asm volatile("s_waitcnt vmcnt(0)" ::: "memory");
        gbar();
        loadA(1, 0); loadB(1, 0); if (nl) stageA(u + 2, 0);
        gbar(); lgkm0(); mfma16(0, 0); gbar();
        loadB(1, 1); if (nl) stageA(u + 2, 1);
        gbar(); lgkm0(); mfma16(0, 1); gbar();
        loadA(1, 1); if (nl) stageB(u + 3, 0);
        gbar(); lgkm0(); mfma16(1, 0); gbar();
        if (nl) stageB(u + 3, 1);
        gbar(); mfma16(1, 1);
        if (nl) asm volatile("s_waitcnt vmcnt(4)" ::: "memory");
        gbar();
    }

    if (mode == 0) {
#pragma unroll
        for (int mi = 0; mi < 8; ++mi) {
            const int row = m0 + wm * 128 + mi * 16 + l4 * 4;
#pragma unroll
            for (int ni = 0; ni < 4; ++ni) {
                const int col = n0q + wn * 64 + ni * 16 + l15;
#pragma unroll
                for (int r = 0; r < 4; ++r)
                    out_q[(size_t)(row + r) * D_MODEL + col] = f2bf(acc[mi][ni][r] * SCALE_Q);
            }
        }
    } else if (mode == 1) {
#pragma unroll
        for (int mi = 0; mi < 8; ++mi) {
            const int row = m0 + wm * 128 + mi * 16 + l4 * 4;
#pragma unroll
            for (int ni = 0; ni < 4; ++ni) {
                const int col = n0q + wn * 64 + ni * 16 + l15;
#pragma unroll
                for (int r = 0; r < 4; ++r)
                    out_k[(size_t)(row + r) * KV_DIM + col] = f2bf(acc[mi][ni][r]);
            }
        }
    } else {
        const int bb = m0 >> 11;
#pragma unroll
        for (int mi = 0; mi < 8; ++mi) {
            const int tok = (m0 & 2047) + wm * 128 + mi * 16 + l4 * 4;
#pragma unroll
            for (int ni = 0; ni < 4; ++ni) {
                const int c = n0q + wn * 64 + ni * 16 + l15;
                const int g = c >> 6, dh = c & 63;
                uint2 pk;
                pk.x = cvtpk(acc[mi][ni][0], acc[mi][ni][1]);
                pk.y = cvtpk(acc[mi][ni][2], acc[mi][ni][3]);
                *reinterpret_cast<uint2*>(out_v + (size_t)((bb * NG + g) * DHEAD + dh) * S_LEN + tok) = pk;
            }
        }
    }
}

// ---------------- out-proj GEMM: 256x128 8-phase, grid 256 = full GPU ----------------
__global__ __launch_bounds__(512, 1) void gemm8o(const unsigned short* __restrict__ A,
                                                 const unsigned short* __restrict__ B,
                                                 float* __restrict__ C) {
    __shared__ __align__(16) char lds[98304];

    const int tid = threadIdx.x;
    const int lane = tid & 63;
    const int w = tid >> 6;
    const int wm = w >> 1, wn = w & 1;
    const int l15 = lane & 15, l4 = lane >> 4;

    int bid = blockIdx.x;
    bid = (bid & 7) * 32 + (bid >> 3);      // bijective XCD swizzle, 256 blocks
    const int mb = bid & 15, nb = bid >> 4;
    const int m0 = mb * 256, n0 = nb * 128;
    const unsigned short* Bp = B + (size_t)n0 * GK;

    const int srow = tid >> 3;
    const int gcol = (((tid & 7) * 16) ^ ((srow & 7) << 4)) >> 1;

    auto stageA = [&](int tile, int half) {
        char* dst = lds + (tile & 1) * 32768 + half * 16384 + tid * 16;
        const unsigned short* src = A + (size_t)(m0 + half * 128 + srow) * GK + tile * 64 + gcol;
        async_copy16(src, dst);
        async_copy16(src + (size_t)64 * GK, dst + 8192);
    };
    auto stageB = [&](int tile, int half) {
        char* dst = lds + 65536 + (tile & 1) * 16384 + half * 8192 + tid * 16;
        const unsigned short* src = Bp + (size_t)(half * 64 + srow) * GK + tile * 64 + gcol;
        async_copy16(src, dst);
    };

    bf16x8 af[2][2], bf[4][2];
    auto loadA2 = [&](int buf, int mhalf) {
        const char* base = lds + buf * 32768;
#pragma unroll
        for (int mi = 0; mi < 2; ++mi) {
            const int r = wm * 64 + mhalf * 32 + mi * 16 + l15;
#pragma unroll
            for (int ks = 0; ks < 2; ++ks)
                af[mi][ks] = *reinterpret_cast<const bf16x8*>(
                    base + r * 128 + ((ks * 64 + l4 * 16) ^ ((r & 7) << 4)));
        }
    };
    auto loadB2 = [&](int buf, int nhalf) {
        const char* base = lds + 65536 + buf * 16384;
#pragma unroll
        for (int ni2 = 0; ni2 < 2; ++ni2) {
            const int ni = nhalf * 2 + ni2;
            const int r = wn * 64 + ni * 16 + l15;
#pragma unroll
            for (int ks = 0; ks < 2; ++ks)
                bf[ni][ks] = *reinterpret_cast<const bf16x8*>(
                    base + r * 128 + ((ks * 64 + l4 * 16) ^ ((r & 7) << 4)));
        }
    };

    f32x4 acc[4][4] = {};
    auto mfma8 = [&](int mq, int nq) {
        __builtin_amdgcn_s_setprio(1);
#pragma unroll
        for (int mi = 0; mi < 2; ++mi)
#pragma unroll
            for (int ni2 = 0; ni2 < 2; ++ni2)
#pragma unroll
                for (int ks = 0; ks < 2; ++ks)
                    acc[mq * 2 + mi][nq * 2 + ni2] = __builtin_amdgcn_mfma_f32_16x16x32_bf16(
                        af[mi][ks], bf[nq * 2 + ni2][ks], acc[mq * 2 + mi][nq * 2 + ni2], 0, 0, 0);
        __builtin_amdgcn_s_setprio(0);
    };

    stageA(0, 0); stageA(0, 1); stageB(0, 0); stageB(0, 1); stageB(1, 0); stageB(1, 1);
    asm volatile("s_waitcnt vmcnt(2)" ::: "memory");
    gbar();

    for (int i = 0; i < 16; ++i) {
        const int u = 2 * i;
        const bool nl = (i < 15);
        loadA2(0, 0); loadB2(0, 0); stageA(u + 1, 0);
        gbar(); lgkm0(); mfma8(0, 0); gbar();
        loadB2(0, 1); stageA(u + 1, 1);
        gbar(); lgkm0(); mfma8(0, 1); gbar();
        loadA2(0, 1); if (nl) stageB(u + 2, 0);
        gbar(); lgkm0(); mfma8(1, 0); gbar();
        if (nl) stageB(u + 2, 1);
        gbar(); mfma8(1, 1);
        if (nl) asm volatile("s_waitcnt vmcnt(2)" ::: "memory");
        else    asm volatile("s_waitcnt vmcnt(0)" ::: "memory");
        gbar();
        loadA2(1, 0); loadB2(1, 0); if (nl) stageA(u + 2, 0);
        gbar(); lgkm0(); mfma8(0, 0); gbar();
        loadB2(1, 1); if (nl) stageA(u + 2, 1);
        gbar(); lgkm0(); mfma8(0, 1); gbar();
        loadA2(1, 1); if (nl) stageB(u + 3, 0);
        gbar(); lgkm0(); mfma8(1, 0); gbar();
        if (nl) stageB(u + 3, 1);
        gbar(); mfma8(1, 1);
        if (nl) asm volatile("s_waitcnt vmcnt(2)" ::: "memory");
        gbar();
    }

#pragma unroll
    for (int mi = 0; mi < 4; ++mi) {
        const int row = m0 + wm * 64 + mi * 16 + l4 * 4;
#pragma unroll
        for (int ni = 0; ni < 4; ++ni) {
            const int col = n0 + wn * 64 + ni * 16 + l15;
#pragma unroll
            for (int r = 0; r < 4; ++r)
                C[(size_t)(row + r) * D_MODEL + col] = acc[mi][ni][r];
        }
    }
}

// ---------------- flash attention v6: KVB=128, 32x32 MFMA, in-register softmax ----
// 512 persistent blocks (2/CU), queue of 768 items, heavy-first. Tile classes
// per (b,head): {8,8,8,7,7,6,6,6,5,5,4,2} 128-wide KV tiles (near-uniform).
__constant__ unsigned char cls2_qi[12]   = {7,7,3,6,6,5,5,2,4,4,1,0};
__constant__ unsigned char cls2_half[12] = {0,1,0,0,1,0,1,0,0,1,0,0};

__global__ __launch_bounds__(512, 2) void attn4_kernel(const unsigned short* __restrict__ qp,
                                                       const unsigned short* __restrict__ kp,
                                                       const unsigned short* __restrict__ vpT,
                                                       unsigned short* __restrict__ attn_out,
                                                       unsigned int* __restrict__ counter,
                                                       unsigned short* __restrict__ partO,
                                                       float* __restrict__ ml) {
    __shared__ __align__(16) unsigned short Ks[2][KVB2 * 64];   // [t][dh] swz, 16KB each
    __shared__ __align__(16) unsigned short Vs[2][64 * KVB2];   // [dh][t] swz, 16KB each
    __shared__ int s_item;

    const int tid = threadIdx.x;
    const int lane = tid & 63;
    const int w = tid >> 6;
    const int l31 = lane & 31, hi = lane >> 5;

    // staging: K rows (tid>>3, +64), chunk tid&7 of 8; V rows (tid>>4, +32), chunk tid&15 of 16
    const int ksr = tid >> 3, ksc = tid & 7;
    const int vsr = tid >> 4, vsc = tid & 15;
    const int kgcol = (((ksc * 16) ^ ((ksr & 7) << 4)) >> 1);
    const int vgcol = (((vsc * 16) ^ ((vsr & 7) << 4)) >> 1);
    char* const kdst0 = (char*)Ks[0] + tid * 16;
    char* const kdst1 = (char*)Ks[1] + tid * 16;
    char* const vdst0 = (char*)Vs[0] + tid * 16;
    char* const vdst1 = (char*)Vs[1] + tid * 16;

    for (;;) {
        if (tid == 0) s_item = (int)atomicAdd(counter, 1u);
        __syncthreads();
        const int item = s_item;
        if (item >= N_ITEMS2) break;
        const int slot = item >> 6;
        const int bh = item & 63;
        const int qi = cls2_qi[slot];
        const int half = cls2_half[slot];
        const bool split = qi >= 4;
        const int b = bh >> 5, head = bh & 31, g = head >> 2;
        const int s0 = qi * QBLK;
        const int m = s0 + w * 32 + l31;
        const int mmin = s0 + w * 32;
        const int mmaxw = mmin + 31;

        int j0, j1;
        if (split) { j0 = half * (qi + 1); j1 = j0 + (qi + 1); }
        else       { j0 = 0;               j1 = 2 * (qi + 1); }

        bf16x8 qf[4];
        {
            const unsigned short* qrow = qp + (size_t)(b * S_LEN + m) * D_MODEL + head * DHEAD + hi * 8;
#pragma unroll
            for (int k = 0; k < 4; ++k)
                qf[k] = *reinterpret_cast<const bf16x8*>(qrow + k * 16);
        }

        const unsigned short* kbase = kp + (size_t)(b * S_LEN + ksr) * KV_DIM + g * DHEAD + kgcol;
        const unsigned short* vbase = vpT + (size_t)((b * NG + g) * DHEAD + vsr) * S_LEN + vgcol;

        float mrun = -1e30f, lrun = 0.f;
        f32x16 o0 = {}, o1 = {};

        // prologue: stage tile j0 into buffer 0 (K rows ksr & ksr+64; V rows vsr & vsr+32)
        async_copy16(kbase + (size_t)j0 * KVB2 * KV_DIM, kdst0);
        async_copy16(kbase + (size_t)(j0 * KVB2 + 64) * KV_DIM, kdst0 + 8192);
        async_copy16(vbase + j0 * KVB2, vdst0);
        async_copy16(vbase + (size_t)32 * S_LEN + j0 * KVB2, vdst0 + 8192);
        asm volatile("s_waitcnt vmcnt(0)" ::: "memory");
        gbar();

        for (int j = j0; j < j1; ++j) {
            const int cur = (j - j0) & 1;
            const int t0 = j * KVB2;
            if (j + 1 < j1) {
                char* kd = cur ? kdst0 : kdst1;
                char* vd = cur ? vdst0 : vdst1;
                async_copy16(kbase + (size_t)(j + 1) * KVB2 * KV_DIM, kd);
                async_copy16(kbase + (size_t)((j + 1) * KVB2 + 64) * KV_DIM, kd + 8192);
                async_copy16(vbase + (j + 1) * KVB2, vd);
                async_copy16(vbase + (size_t)32 * S_LEN + (j + 1) * KVB2, vd + 8192);
            }

            if (t0 <= mmaxw) {
                const char* Kb = (const char*)Ks[cur];
                const char* Vb = (const char*)Vs[cur];
                const int rswz = (l31 & 7) << 4;

                // subtile state: computed iff t0+32tt <= mmaxw; element-mask iff t0+32tt+31 > mmin
                bool cmp[4], emk[4];
#pragma unroll
                for (int tt = 0; tt < 4; ++tt) {
                    cmp[tt] = (t0 + 32 * tt) <= mmaxw;
                    emk[tt] = (t0 + 32 * tt + 31) > mmin;
                }

                // ---- S^T = mfma_32x32x16(K, Q), 4 k-steps x 4 t-subtiles ----
                f32x16 sv[4] = {};
#pragma unroll
                for (int k = 0; k < 4; ++k) {
                    const int coff = k * 32 + hi * 16;
#pragma unroll
                    for (int tt = 0; tt < 4; ++tt) {
                        if (!cmp[tt]) continue;
                        const bf16x8 kf = *reinterpret_cast<const bf16x8*>(
                            Kb + (tt * 32 + l31) * 128 + (coff ^ rswz));
                        sv[tt] = __builtin_amdgcn_mfma_f32_32x32x16_bf16(kf, qf[k], sv[tt], 0, 0, 0);
                    }
                }

                // ---- in-register online softmax (exp2 domain) ----
                float rmax = -1e30f;
#pragma unroll
                for (int tt = 0; tt < 4; ++tt) {
                    if (!cmp[tt]) continue;
                    if (emk[tt]) {
#pragma unroll
                        for (int r = 0; r < 16; ++r) {
                            const int tloc = tt * 32 + (r & 3) + 8 * (r >> 2) + 4 * hi;
                            float v = sv[tt][r];
                            if (t0 + tloc > m) v = -1e30f;
                            sv[tt][r] = v;
                            rmax = fmaxf(rmax, v);
                        }
                    } else {
#pragma unroll
                        for (int r = 0; r < 16; ++r)
                            rmax = fmaxf(rmax, sv[tt][r]);
                    }
                }
                rmax = fmaxf(rmax, __shfl_xor(rmax, 32, 64));
                if (!__all(rmax <= mrun + 8.0f)) {   // T13 defer-max
                    const float mnew = fmaxf(mrun, rmax);
                    const float corr = __builtin_amdgcn_exp2f(mrun - mnew);
                    lrun *= corr;
#pragma unroll
                    for (int r = 0; r < 16; ++r) { o0[r] *= corr; o1[r] *= corr; }
                    mrun = mnew;
                }
                float rs = 0.f;
#pragma unroll
                for (int tt = 0; tt < 4; ++tt) {
                    if (!cmp[tt]) continue;
#pragma unroll
                    for (int r = 0; r < 16; ++r) {
                        const float p = __builtin_amdgcn_exp2f(sv[tt][r] - mrun);
                        sv[tt][r] = p;
                        rs += p;
                    }
                }
                rs += __shfl_xor(rs, 32, 64);
                lrun += rs;

                // ---- O^T += mfma_32x32x16(V, P); P built in-register ----
#pragma unroll
                for (int c = 0; c < 8; ++c) {
                    const int tt = c >> 1;
                    if (!cmp[tt]) continue;
                    const int h8 = (c & 1) * 8;
                    uint32_t a0 = cvtpk(sv[tt][h8 + 0], sv[tt][h8 + 1]);
                    uint32_t a1 = cvtpk(sv[tt][h8 + 2], sv[tt][h8 + 3]);
                    uint32_t b0 = cvtpk(sv[tt][h8 + 4], sv[tt][h8 + 5]);
                    uint32_t b1 = cvtpk(sv[tt][h8 + 6], sv[tt][h8 + 7]);
                    plswap(a0, b0); plswap(a1, b1);
                    union { uint32_t w4[4]; bf16x8 v; } pf;
                    pf.w4[0] = a0; pf.w4[1] = a1; pf.w4[2] = b0; pf.w4[3] = b1;
                    const int coff = c * 32 + hi * 16;
                    const bf16x8 vf0 = *reinterpret_cast<const bf16x8*>(
                        Vb + l31 * 256 + (coff ^ rswz));
                    o0 = __builtin_amdgcn_mfma_f32_32x32x16_bf16(vf0, pf.v, o0, 0, 0, 0);
                    const bf16x8 vf1 = *reinterpret_cast<const bf16x8*>(
                        Vb + (32 + l31) * 256 + (coff ^ rswz));
                    o1 = __builtin_amdgcn_mfma_f32_32x32x16_bf16(vf1, pf.v, o1, 0, 0, 0);
                }
            }
            asm volatile("s_waitcnt vmcnt(0)" ::: "memory");
            gbar();
        }

        if (split) {
            const int pb = ((bh << 2) + (qi - 4)) * 2 + half;
            const int mrow = w * 32 + l31;
            if (hi == 0) {
                ml[pb * 512 + mrow] = mrun;
                ml[pb * 512 + 256 + mrow] = lrun;
            }
            unsigned short* dst = partO + (size_t)pb * 16384 + mrow * 64 + hi * 4;
#pragma unroll
            for (int qd = 0; qd < 4; ++qd) {
                uint2 pk0, pk1;
                pk0.x = cvtpk(o0[4 * qd + 0], o0[4 * qd + 1]);
                pk0.y = cvtpk(o0[4 * qd + 2], o0[4 * qd + 3]);
                pk1.x = cvtpk(o1[4 * qd + 0], o1[4 * qd + 1]);
                pk1.y = cvtpk(o1[4 * qd + 2], o1[4 * qd + 3]);
                *reinterpret_cast<uint2*>(dst + 8 * qd) = pk0;
                *reinterpret_cast<uint2*>(dst + 32 + 8 * qd) = pk1;
            }
        } else {
            const float inv = 1.0f / lrun;
            unsigned short* dst = attn_out + (size_t)(b * S_LEN + m) * D_MODEL + head * DHEAD + hi * 4;
#pragma unroll
            for (int qd = 0; qd < 4; ++qd) {
                uint2 pk0, pk1;
                pk0.x = cvtpk(o0[4 * qd + 0] * inv, o0[4 * qd + 1] * inv);
                pk0.y = cvtpk(o0[4 * qd + 2] * inv, o0[4 * qd + 3] * inv);
                pk1.x = cvtpk(o1[4 * qd + 0] * inv, o1[4 * qd + 1] * inv);
                pk1.y = cvtpk(o1[4 * qd + 2] * inv, o1[4 * qd + 3] * inv);
                *reinterpret_cast<uint2*>(dst + 8 * qd) = pk0;
                *reinterpret_cast<uint2*>(dst + 32 + 8 * qd) = pk1;
            }
        }
    }
}

// ---------------- merge two KV-halves (qi>=4) ----------------
__global__ __launch_bounds__(512) void merge2_kernel(const unsigned short* __restrict__ partO,
                                                     const float* __restrict__ ml,
                                                     unsigned short* __restrict__ attn_out) {
    const int blk = blockIdx.x;
    const int bh = blk >> 2;
    const int qi = (blk & 3) + 4;
    const int b = bh >> 5, head = bh & 31;
    const int s0 = qi * QBLK;
    const int tid = threadIdx.x;
    const int row = tid >> 1, dh0 = (tid & 1) * 32;
    const int pb0 = blk * 2, pb1 = pb0 + 1;

    const float m0 = ml[pb0 * 512 + row], l0 = ml[pb0 * 512 + 256 + row];
    const float m1 = ml[pb1 * 512 + row], l1 = ml[pb1 * 512 + 256 + row];
    const float M = fmaxf(m0, m1);
    float w0 = __builtin_amdgcn_exp2f(m0 - M);
    float w1 = __builtin_amdgcn_exp2f(m1 - M);
    const float inv = 1.0f / (l0 * w0 + l1 * w1);
    w0 *= inv; w1 *= inv;

    const uint4* p0 = reinterpret_cast<const uint4*>(partO + (size_t)pb0 * 16384 + row * 64 + dh0);
    const uint4* p1 = reinterpret_cast<const uint4*>(partO + (size_t)pb1 * 16384 + row * 64 + dh0);
    unsigned short* dst = attn_out + (size_t)(b * S_LEN + s0 + row) * D_MODEL + head * DHEAD + dh0;
#pragma unroll
    for (int c = 0; c < 4; ++c) {
        union { unsigned short u[8]; uint4 v; } ua, ub, uo;
        ua.v = p0[c]; ub.v = p1[c];
#pragma unroll
        for (int e = 0; e < 8; e += 2) {
            float x0 = bf2f(ua.u[e]) * w0 + bf2f(ub.u[e]) * w1;
            float x1 = bf2f(ua.u[e + 1]) * w0 + bf2f(ub.u[e + 1]) * w1;
            reinterpret_cast<uint32_t*>(uo.u)[e >> 1] = cvtpk(x0, x1);
        }
        reinterpret_cast<uint4*>(dst)[c] = uo.v;
    }
}

// ---------------- host launch ----------------
extern "C" void kernel_launch(void* const* d_in, const int* in_sizes, int n_in,
                              void* d_out, int out_size, void* d_ws, size_t ws_size,
                              hipStream_t stream) {
    const float* q     = (const float*)d_in[0];
    const float* k     = (const float*)d_in[1];
    const float* v     = (const float*)d_in[2];
    const float* w_q   = (const float*)d_in[4];
    const float* w_k   = (const float*)d_in[5];
    const float* w_v   = (const float*)d_in[6];
    const float* w_out = (const float*)d_in[7];

    char* ws = (char*)d_ws;
    size_t off = 0;
    auto alloc = [&](size_t n) { char* p = ws + off; off += (n + 255) & ~(size_t)255; return p; };
    unsigned short* qb   = (unsigned short*)alloc((size_t)M_TOK * D_MODEL * 2);  // partO after proj
    unsigned short* kb   = (unsigned short*)alloc((size_t)M_TOK * D_MODEL * 2);
    unsigned short* vb   = (unsigned short*)alloc((size_t)M_TOK * D_MODEL * 2);
    unsigned short* wqb  = (unsigned short*)alloc((size_t)D_MODEL * D_MODEL * 2);
    unsigned short* wkvb = (unsigned short*)alloc((size_t)2 * KV_DIM * D_MODEL * 2);
    unsigned short* wob  = (unsigned short*)alloc((size_t)D_MODEL * D_MODEL * 2);
    unsigned short* qpb  = (unsigned short*)alloc((size_t)M_TOK * D_MODEL * 2);
    unsigned short* kpb  = (unsigned short*)alloc((size_t)M_TOK * KV_DIM * 2);
    unsigned short* vtb  = (unsigned short*)alloc((size_t)M_TOK * KV_DIM * 2);
    unsigned short* aob  = (unsigned short*)alloc((size_t)M_TOK * D_MODEL * 2);
    float*          mlb  = (float*)alloc((size_t)512 * 512 * 4);
    unsigned int*   cnt  = (unsigned int*)alloc(256);

    cvt_all<<<dim3(17408), dim3(256), 0, stream>>>(q, k, v, w_q, w_k, w_v, w_out,
                                                   qb, kb, vb, wqb, wkvb, wob, cnt);

    gemm8p<<<dim3(192), dim3(512), 0, stream>>>(qb, kb, vb, wqb, wkvb, qpb, kpb, vtb);

    attn4_kernel<<<dim3(512), dim3(512), 0, stream>>>(qpb, kpb, vtb, aob, cnt, qb, mlb);
    merge2_kernel<<<dim3(256), dim3(512), 0, stream>>>(qb, mlb, aob);

    gemm8o<<<dim3(256), dim3(512), 0, stream>>>(aob, wob, (float*)d_out);
}

// Round 9
// 190.642 us; speedup vs baseline: 1.0556x; 1.0556x over previous
//
#include <hip/hip_runtime.h>
#include <hip/hip_bf16.h>
#include <stdint.h>

#define B_SZ 2
#define S_LEN 2048
#define D_MODEL 2048
#define NH 32
#define NG 8
#define HGRP 4
#define DHEAD 64
#define KV_DIM 512       // NG*DHEAD
#define M_TOK 4096       // B_SZ*S_LEN
#define KVB 64           // attention KV tile
#define QBLK 256

typedef __attribute__((ext_vector_type(8))) short bf16x8;
typedef __attribute__((ext_vector_type(4))) float f32x4;
typedef __attribute__((ext_vector_type(16))) float f32x16;

__device__ inline unsigned short f2bf(float x) {
    uint32_t u = __builtin_bit_cast(uint32_t, x);
    uint32_t r = (u + 0x7fffu + ((u >> 16) & 1u)) >> 16;
    return (unsigned short)r;
}

__device__ inline uint32_t cvtpk(float lo, float hi) {
    uint32_t r;
    asm("v_cvt_pk_bf16_f32 %0, %1, %2" : "=v"(r) : "v"(lo), "v"(hi));
    return r;
}

__device__ inline void plswap(uint32_t& a, uint32_t& b) {
    asm volatile("v_permlane32_swap_b32 %0, %1" : "+v"(a), "+v"(b));
}

__device__ inline float bf2f(unsigned short u) {
    uint32_t x = ((uint32_t)u) << 16;
    return __builtin_bit_cast(float, x);
}

__device__ inline void async_copy16(const void* g, void* l) {
    __builtin_amdgcn_global_load_lds(
        (const __attribute__((address_space(1))) void*)g,
        (__attribute__((address_space(3))) void*)l,
        16, 0, 0);
}

__device__ inline void gbar() {
    asm volatile("" ::: "memory");
    __builtin_amdgcn_s_barrier();
    asm volatile("" ::: "memory");
}
__device__ inline void lgkm0() {
    asm volatile("s_waitcnt lgkmcnt(0)" ::: "memory");
    __builtin_amdgcn_sched_barrier(0);
}

// ---------------- fused f32 -> bf16 convert (all 7 tensors) ----------------
__global__ __launch_bounds__(256) void cvt_all(const float* __restrict__ q,
                                               const float* __restrict__ k,
                                               const float* __restrict__ v,
                                               const float* __restrict__ wq,
                                               const float* __restrict__ wk,
                                               const float* __restrict__ wv,
                                               const float* __restrict__ wo,
                                               unsigned short* __restrict__ qb,
                                               unsigned short* __restrict__ kb,
                                               unsigned short* __restrict__ vb,
                                               unsigned short* __restrict__ wqb,
                                               unsigned short* __restrict__ wkvb,
                                               unsigned short* __restrict__ wob) {
    const int i = blockIdx.x * 256 + threadIdx.x;
    const float* src; unsigned short* dst; int j;
    if (i < 1048576)      { src = q;  dst = qb;  j = i; }
    else if (i < 2097152) { src = k;  dst = kb;  j = i - 1048576; }
    else if (i < 3145728) { src = v;  dst = vb;  j = i - 2097152; }
    else if (i < 3670016) { src = wq; dst = wqb; j = i - 3145728; }
    else if (i < 3801088) { src = wk; dst = wkvb; j = i - 3670016; }
    else if (i < 3932160) { src = wv; dst = wkvb + (size_t)KV_DIM * D_MODEL; j = i - 3801088; }
    else                  { src = wo; dst = wob; j = i - 3932160; }
    const float4* p = reinterpret_cast<const float4*>(src) + (size_t)j * 2;
    float4 a = p[0], b = p[1];
    union { unsigned short u[8]; uint4 v4; } r;
    r.u[0] = f2bf(a.x); r.u[1] = f2bf(a.y); r.u[2] = f2bf(a.z); r.u[3] = f2bf(a.w);
    r.u[4] = f2bf(b.x); r.u[5] = f2bf(b.y); r.u[6] = f2bf(b.z); r.u[7] = f2bf(b.w);
    reinterpret_cast<uint4*>(dst)[j] = r.v4;
}

#define SCALE_Q 0.1803368867f   // 0.125 * log2(e)
#define GK 2048

// ---------------- proj GEMM: 256x256 8-phase, N-stacked q|k|v ----------------
__global__ __launch_bounds__(512, 2) void gemm8p(const unsigned short* __restrict__ Aq,
                                                 const unsigned short* __restrict__ Ak,
                                                 const unsigned short* __restrict__ Av,
                                                 const unsigned short* __restrict__ Bq,
                                                 const unsigned short* __restrict__ Bkv,
                                                 unsigned short* __restrict__ out_q,
                                                 unsigned short* __restrict__ out_k,
                                                 unsigned short* __restrict__ out_v) {
    __shared__ __align__(16) char lds[131072];

    const int tid = threadIdx.x;
    const int lane = tid & 63;
    const int w = tid >> 6;
    const int wm = w >> 2, wn = w & 3;
    const int l15 = lane & 15, l4 = lane >> 4;

    int bid = blockIdx.x;
    bid = (bid & 7) * 24 + (bid >> 3);      // bijective XCD swizzle, 192 blocks
    const int mb = bid & 15, nb = bid >> 4;
    const int m0 = mb * 256;

    const unsigned short* Ap;
    const unsigned short* Bp;
    int mode = 0, n0q = 0;
    if (nb < 8) {
        Ap = Aq; Bp = Bq + (size_t)(nb * 256) * GK; mode = 0; n0q = nb * 256;
    } else if (nb < 10) {
        Ap = Ak; Bp = Bkv + (size_t)((nb - 8) * 256) * GK; mode = 1; n0q = (nb - 8) * 256;
    } else {
        Ap = Av; Bp = Bkv + (size_t)((nb - 10) * 256 + 512) * GK; mode = 2; n0q = (nb - 10) * 256;
    }

    const int srow = tid >> 3;
    const int gcol = (((tid & 7) * 16) ^ ((srow & 7) << 4)) >> 1;
    char* const myl = lds + tid * 16;

    auto stageA = [&](int tile, int half) {
        char* dst = myl + (tile & 1) * 32768 + half * 16384;
        const unsigned short* src = Ap + (size_t)(m0 + half * 128 + srow) * GK + tile * 64 + gcol;
        async_copy16(src, dst);
        async_copy16(src + (size_t)64 * GK, dst + 8192);
    };
    auto stageB = [&](int tile, int half) {
        char* dst = myl + 65536 + (tile & 1) * 32768 + half * 16384;
        const unsigned short* src = Bp + (size_t)(half * 128 + srow) * GK + tile * 64 + gcol;
        async_copy16(src, dst);
        async_copy16(src + (size_t)64 * GK, dst + 8192);
    };

    bf16x8 af[4][2], bf[4][2];
    auto loadA = [&](int buf, int mhalf) {
        const char* base = lds + buf * 32768;
#pragma unroll
        for (int mi = 0; mi < 4; ++mi) {
            const int r = wm * 128 + mhalf * 64 + mi * 16 + l15;
#pragma unroll
            for (int ks = 0; ks < 2; ++ks)
                af[mi][ks] = *reinterpret_cast<const bf16x8*>(
                    base + r * 128 + ((ks * 64 + l4 * 16) ^ ((r & 7) << 4)));
        }
    };
    auto loadB = [&](int buf, int nhalf) {
        const char* base = lds + 65536 + buf * 32768;
#pragma unroll
        for (int ni2 = 0; ni2 < 2; ++ni2) {
            const int ni = nhalf * 2 + ni2;
            const int r = wn * 64 + ni * 16 + l15;
#pragma unroll
            for (int ks = 0; ks < 2; ++ks)
                bf[ni][ks] = *reinterpret_cast<const bf16x8*>(
                    base + r * 128 + ((ks * 64 + l4 * 16) ^ ((r & 7) << 4)));
        }
    };

    f32x4 acc[8][4] = {};
    auto mfma16 = [&](int mq, int nq) {
        __builtin_amdgcn_s_setprio(1);
#pragma unroll
        for (int mi = 0; mi < 4; ++mi)
#pragma unroll
            for (int ni2 = 0; ni2 < 2; ++ni2)
#pragma unroll
                for (int ks = 0; ks < 2; ++ks)
                    acc[mq * 4 + mi][nq * 2 + ni2] = __builtin_amdgcn_mfma_f32_16x16x32_bf16(
                        af[mi][ks], bf[nq * 2 + ni2][ks], acc[mq * 4 + mi][nq * 2 + ni2], 0, 0, 0);
        __builtin_amdgcn_s_setprio(0);
    };

    stageA(0, 0); stageA(0, 1); stageB(0, 0); stageB(0, 1); stageB(1, 0); stageB(1, 1);
    asm volatile("s_waitcnt vmcnt(4)" ::: "memory");
    gbar();

    for (int i = 0; i < 16; ++i) {
        const int u = 2 * i;
        const bool nl = (i < 15);
        loadA(0, 0); loadB(0, 0); stageA(u + 1, 0);
        gbar(); lgkm0(); mfma16(0, 0); gbar();
        loadB(0, 1); stageA(u + 1, 1);
        gbar(); lgkm0(); mfma16(0, 1); gbar();
        loadA(0, 1); if (nl) stageB(u + 2, 0);
        gbar(); lgkm0(); mfma16(1, 0); gbar();
        if (nl) stageB(u + 2, 1);
        gbar(); mfma16(1, 1);
        if (nl) asm volatile("s_waitcnt vmcnt(4)" ::: "memory");
        else    asm volatile("s_waitcnt vmcnt(0)" ::: "memory");
        gbar();
        loadA(1, 0); loadB(1, 0); if (nl) stageA(u + 2, 0);
        gbar(); lgkm0(); mfma16(0, 0); gbar();
        loadB(1, 1); if (nl) stageA(u + 2, 1);
        gbar(); lgkm0(); mfma16(0, 1); gbar();
        loadA(1, 1); if (nl) stageB(u + 3, 0);
        gbar(); lgkm0(); mfma16(1, 0); gbar();
        if (nl) stageB(u + 3, 1);
        gbar(); mfma16(1, 1);
        if (nl) asm volatile("s_waitcnt vmcnt(4)" ::: "memory");
        gbar();
    }

    if (mode == 0) {
#pragma unroll
        for (int mi = 0; mi < 8; ++mi) {
            const int row = m0 + wm * 128 + mi * 16 + l4 * 4;
#pragma unroll
            for (int ni = 0; ni < 4; ++ni) {
                const int col = n0q + wn * 64 + ni * 16 + l15;
#pragma unroll
                for (int r = 0; r < 4; ++r)
                    out_q[(size_t)(row + r) * D_MODEL + col] = f2bf(acc[mi][ni][r] * SCALE_Q);
            }
        }
    } else if (mode == 1) {
#pragma unroll
        for (int mi = 0; mi < 8; ++mi) {
            const int row = m0 + wm * 128 + mi * 16 + l4 * 4;
#pragma unroll
            for (int ni = 0; ni < 4; ++ni) {
                const int col = n0q + wn * 64 + ni * 16 + l15;
#pragma unroll
                for (int r = 0; r < 4; ++r)
                    out_k[(size_t)(row + r) * KV_DIM + col] = f2bf(acc[mi][ni][r]);
            }
        }
    } else {
        const int bb = m0 >> 11;
#pragma unroll
        for (int mi = 0; mi < 8; ++mi) {
            const int tok = (m0 & 2047) + wm * 128 + mi * 16 + l4 * 4;
#pragma unroll
            for (int ni = 0; ni < 4; ++ni) {
                const int c = n0q + wn * 64 + ni * 16 + l15;
                const int g = c >> 6, dh = c & 63;
                uint2 pk;
                pk.x = cvtpk(acc[mi][ni][0], acc[mi][ni][1]);
                pk.y = cvtpk(acc[mi][ni][2], acc[mi][ni][3]);
                *reinterpret_cast<uint2*>(out_v + (size_t)((bb * NG + g) * DHEAD + dh) * S_LEN + tok) = pk;
            }
        }
    }
}

// ---------------- out-proj GEMM: 256x128 8-phase, grid 256 = full GPU ----------------
__global__ __launch_bounds__(512, 1) void gemm8o(const unsigned short* __restrict__ A,
                                                 const unsigned short* __restrict__ B,
                                                 float* __restrict__ C) {
    __shared__ __align__(16) char lds[98304];

    const int tid = threadIdx.x;
    const int lane = tid & 63;
    const int w = tid >> 6;
    const int wm = w >> 1, wn = w & 1;
    const int l15 = lane & 15, l4 = lane >> 4;

    int bid = blockIdx.x;
    bid = (bid & 7) * 32 + (bid >> 3);      // bijective XCD swizzle, 256 blocks
    const int mb = bid & 15, nb = bid >> 4;
    const int m0 = mb * 256, n0 = nb * 128;
    const unsigned short* Bp = B + (size_t)n0 * GK;

    const int srow = tid >> 3;
    const int gcol = (((tid & 7) * 16) ^ ((srow & 7) << 4)) >> 1;

    auto stageA = [&](int tile, int half) {
        char* dst = lds + (tile & 1) * 32768 + half * 16384 + tid * 16;
        const unsigned short* src = A + (size_t)(m0 + half * 128 + srow) * GK + tile * 64 + gcol;
        async_copy16(src, dst);
        async_copy16(src + (size_t)64 * GK, dst + 8192);
    };
    auto stageB = [&](int tile, int half) {
        char* dst = lds + 65536 + (tile & 1) * 16384 + half * 8192 + tid * 16;
        const unsigned short* src = Bp + (size_t)(half * 64 + srow) * GK + tile * 64 + gcol;
        async_copy16(src, dst);
    };

    bf16x8 af[2][2], bf[4][2];
    auto loadA2 = [&](int buf, int mhalf) {
        const char* base = lds + buf * 32768;
#pragma unroll
        for (int mi = 0; mi < 2; ++mi) {
            const int r = wm * 64 + mhalf * 32 + mi * 16 + l15;
#pragma unroll
            for (int ks = 0; ks < 2; ++ks)
                af[mi][ks] = *reinterpret_cast<const bf16x8*>(
                    base + r * 128 + ((ks * 64 + l4 * 16) ^ ((r & 7) << 4)));
        }
    };
    auto loadB2 = [&](int buf, int nhalf) {
        const char* base = lds + 65536 + buf * 16384;
#pragma unroll
        for (int ni2 = 0; ni2 < 2; ++ni2) {
            const int ni = nhalf * 2 + ni2;
            const int r = wn * 64 + ni * 16 + l15;
#pragma unroll
            for (int ks = 0; ks < 2; ++ks)
                bf[ni][ks] = *reinterpret_cast<const bf16x8*>(
                    base + r * 128 + ((ks * 64 + l4 * 16) ^ ((r & 7) << 4)));
        }
    };

    f32x4 acc[4][4] = {};
    auto mfma8 = [&](int mq, int nq) {
        __builtin_amdgcn_s_setprio(1);
#pragma unroll
        for (int mi = 0; mi < 2; ++mi)
#pragma unroll
            for (int ni2 = 0; ni2 < 2; ++ni2)
#pragma unroll
                for (int ks = 0; ks < 2; ++ks)
                    acc[mq * 2 + mi][nq * 2 + ni2] = __builtin_amdgcn_mfma_f32_16x16x32_bf16(
                        af[mi][ks], bf[nq * 2 + ni2][ks], acc[mq * 2 + mi][nq * 2 + ni2], 0, 0, 0);
        __builtin_amdgcn_s_setprio(0);
    };

    stageA(0, 0); stageA(0, 1); stageB(0, 0); stageB(0, 1); stageB(1, 0); stageB(1, 1);
    asm volatile("s_waitcnt vmcnt(2)" ::: "memory");
    gbar();

    for (int i = 0; i < 16; ++i) {
        const int u = 2 * i;
        const bool nl = (i < 15);
        loadA2(0, 0); loadB2(0, 0); stageA(u + 1, 0);
        gbar(); lgkm0(); mfma8(0, 0); gbar();
        loadB2(0, 1); stageA(u + 1, 1);
        gbar(); lgkm0(); mfma8(0, 1); gbar();
        loadA2(0, 1); if (nl) stageB(u + 2, 0);
        gbar(); lgkm0(); mfma8(1, 0); gbar();
        if (nl) stageB(u + 2, 1);
        gbar(); mfma8(1, 1);
        if (nl) asm volatile("s_waitcnt vmcnt(2)" ::: "memory");
        else    asm volatile("s_waitcnt vmcnt(0)" ::: "memory");
        gbar();
        loadA2(1, 0); loadB2(1, 0); if (nl) stageA(u + 2, 0);
        gbar(); lgkm0(); mfma8(0, 0); gbar();
        loadB2(1, 1); if (nl) stageA(u + 2, 1);
        gbar(); lgkm0(); mfma8(0, 1); gbar();
        loadA2(1, 1); if (nl) stageB(u + 3, 0);
        gbar(); lgkm0(); mfma8(1, 0); gbar();
        if (nl) stageB(u + 3, 1);
        gbar(); mfma8(1, 1);
        if (nl) asm volatile("s_waitcnt vmcnt(2)" ::: "memory");
        gbar();
    }

#pragma unroll
    for (int mi = 0; mi < 4; ++mi) {
        const int row = m0 + wm * 64 + mi * 16 + l4 * 4;
#pragma unroll
        for (int ni = 0; ni < 4; ++ni) {
            const int col = n0 + wn * 64 + ni * 16 + l15;
#pragma unroll
            for (int r = 0; r < 4; ++r)
                C[(size_t)(row + r) * D_MODEL + col] = acc[mi][ni][r];
        }
    }
}

// ---------------- flash attention v7: KVB=64, 32x32 MFMA, static balanced split ----
// 1024 items (16 parts per (b,head)) = exactly 4 blocks/CU residency. Part sizes
// chosen so round-robin CU groups sum to 36/36/37/35 tiles. qi>=2 parts merged.
__constant__ unsigned char sl_qi[16] = {7,7,7,6,6,6,5,5,4,4,3,3,2,2,1,0};
__constant__ unsigned char sl_j0[16] = {0,11,22,0,10,19,0,11,0,10,0,8,0,6,0,0};
__constant__ unsigned char sl_j1[16] = {11,22,32,10,19,28,11,24,10,20,8,16,6,12,8,4};
__constant__ unsigned char sl_pt[16] = {0,1,2,0,1,2,0,1,0,1,0,1,0,1,0,0};
// pb base per qi (within 14 parts/bh): qi2:0 qi3:2 qi4:4 qi5:6 qi6:8 qi7:11

__global__ __launch_bounds__(512, 4) void attn5_kernel(const unsigned short* __restrict__ qp,
                                                       const unsigned short* __restrict__ kp,
                                                       const unsigned short* __restrict__ vpT,
                                                       unsigned short* __restrict__ attn_out,
                                                       unsigned short* __restrict__ partO,
                                                       float* __restrict__ ml) {
    __shared__ __align__(16) unsigned short Ks[2][KVB * 64];
    __shared__ __align__(16) unsigned short Vs[2][KVB * 64];

    const int tid = threadIdx.x;
    const int lane = tid & 63;
    const int w = tid >> 6;
    const int l31 = lane & 31, hi = lane >> 5;
    const int sr = tid >> 3, sc = tid & 7;
    const int sgcol = (((sc * 16) ^ ((sr & 7) << 4)) >> 1);
    char* const kdst0 = (char*)Ks[0] + tid * 16;
    char* const kdst1 = (char*)Ks[1] + tid * 16;
    char* const vdst0 = (char*)Vs[0] + tid * 16;
    char* const vdst1 = (char*)Vs[1] + tid * 16;

    const int item = blockIdx.x;
    const int slot = item >> 6;
    const int bh = item & 63;
    const int qi = sl_qi[slot];
    const int j0 = sl_j0[slot];
    const int j1 = sl_j1[slot];
    const int part = sl_pt[slot];
    const bool merged = (qi >= 2);
    const int b = bh >> 5, head = bh & 31, g = head >> 2;
    const int s0 = qi * QBLK;
    const int m = s0 + w * 32 + l31;
    const int mmin = s0 + w * 32;
    const int mmaxw = mmin + 31;

    bf16x8 qf[4];
    {
        const unsigned short* qrow = qp + (size_t)(b * S_LEN + m) * D_MODEL + head * DHEAD + hi * 8;
#pragma unroll
        for (int k = 0; k < 4; ++k)
            qf[k] = *reinterpret_cast<const bf16x8*>(qrow + k * 16);
    }

    const unsigned short* kbase = kp + (size_t)(b * S_LEN + sr) * KV_DIM + g * DHEAD + sgcol;
    const unsigned short* vbase = vpT + (size_t)((b * NG + g) * DHEAD + sr) * S_LEN + sgcol;

    float mrun = -1e30f, lrun = 0.f;
    f32x16 o0 = {}, o1 = {};

    async_copy16(kbase + (size_t)j0 * KVB * KV_DIM, kdst0);
    async_copy16(vbase + j0 * KVB, vdst0);
    asm volatile("s_waitcnt vmcnt(0)" ::: "memory");
    gbar();

    for (int j = j0; j < j1; ++j) {
        const int cur = (j - j0) & 1;
        const int t0 = j * KVB;
        if (j + 1 < j1) {
            async_copy16(kbase + (size_t)(j + 1) * KVB * KV_DIM, cur ? kdst0 : kdst1);
            async_copy16(vbase + (j + 1) * KVB, cur ? vdst0 : vdst1);
        }

        const bool tt0 = (t0 <= mmaxw);
        const bool tt1 = (t0 + 32 <= mmaxw);
        if (tt0) {
            const char* Kb = (const char*)Ks[cur];
            const char* Vb = (const char*)Vs[cur];
            const int rswz0 = (l31 & 7) << 4;

            // ---- S^T = mfma_32x32x16(K, Q) ----
            f32x16 s0v = {}, s1v = {};
#pragma unroll
            for (int k = 0; k < 4; ++k) {
                const int coff = k * 32 + hi * 16;
                const bf16x8 kf0 = *reinterpret_cast<const bf16x8*>(
                    Kb + l31 * 128 + (coff ^ rswz0));
                s0v = __builtin_amdgcn_mfma_f32_32x32x16_bf16(kf0, qf[k], s0v, 0, 0, 0);
                if (tt1) {
                    const bf16x8 kf1 = *reinterpret_cast<const bf16x8*>(
                        Kb + (32 + l31) * 128 + (coff ^ rswz0));
                    s1v = __builtin_amdgcn_mfma_f32_32x32x16_bf16(kf1, qf[k], s1v, 0, 0, 0);
                }
            }

            // ---- in-register online softmax (mask hoisted) ----
            const bool msk = (t0 + KVB - 1) > mmin;
            float rmax = -1e30f;
            if (msk) {
#pragma unroll
                for (int r = 0; r < 16; ++r) {
                    const int tloc = (r & 3) + 8 * (r >> 2) + 4 * hi;
                    float v = s0v[r];
                    if (t0 + tloc > m) v = -1e30f;
                    s0v[r] = v;
                    rmax = fmaxf(rmax, v);
                }
                if (tt1) {
#pragma unroll
                    for (int r = 0; r < 16; ++r) {
                        const int tloc = 32 + (r & 3) + 8 * (r >> 2) + 4 * hi;
                        float v = s1v[r];
                        if (t0 + tloc > m) v = -1e30f;
                        s1v[r] = v;
                        rmax = fmaxf(rmax, v);
                    }
                }
            } else {
#pragma unroll
                for (int r = 0; r < 16; ++r)
                    rmax = fmaxf(rmax, s0v[r]);
                if (tt1) {
#pragma unroll
                    for (int r = 0; r < 16; ++r)
                        rmax = fmaxf(rmax, s1v[r]);
                }
            }
            rmax = fmaxf(rmax, __shfl_xor(rmax, 32, 64));
            if (!__all(rmax <= mrun + 8.0f)) {   // T13 defer-max
                const float mnew = fmaxf(mrun, rmax);
                const float corr = __builtin_amdgcn_exp2f(mrun - mnew);
                lrun *= corr;
#pragma unroll
                for (int r = 0; r < 16; ++r) { o0[r] *= corr; o1[r] *= corr; }
                mrun = mnew;
            }
            float rs = 0.f;
#pragma unroll
            for (int r = 0; r < 16; ++r) {
                const float p = __builtin_amdgcn_exp2f(s0v[r] - mrun);
                s0v[r] = p;
                rs += p;
            }
            if (tt1) {
#pragma unroll
                for (int r = 0; r < 16; ++r) {
                    const float p = __builtin_amdgcn_exp2f(s1v[r] - mrun);
                    s1v[r] = p;
                    rs += p;
                }
            }
            rs += __shfl_xor(rs, 32, 64);
            lrun += rs;

            // ---- O^T += mfma_32x32x16(V, P); P built in-register ----
#pragma unroll
            for (int c = 0; c < 4; ++c) {
                if (c >= 2 && !tt1) break;
                const f32x16& sv = (c >> 1) ? s1v : s0v;
                const int h8 = (c & 1) * 8;
                uint32_t a0 = cvtpk(sv[h8 + 0], sv[h8 + 1]);
                uint32_t a1 = cvtpk(sv[h8 + 2], sv[h8 + 3]);
                uint32_t b0 = cvtpk(sv[h8 + 4], sv[h8 + 5]);
                uint32_t b1 = cvtpk(sv[h8 + 6], sv[h8 + 7]);
                plswap(a0, b0); plswap(a1, b1);
                union { uint32_t w4[4]; bf16x8 v; } pf;
                pf.w4[0] = a0; pf.w4[1] = a1; pf.w4[2] = b0; pf.w4[3] = b1;
                const int coff = c * 32 + hi * 16;
                const bf16x8 vf0 = *reinterpret_cast<const bf16x8*>(
                    Vb + l31 * 128 + (coff ^ rswz0));
                o0 = __builtin_amdgcn_mfma_f32_32x32x16_bf16(vf0, pf.v, o0, 0, 0, 0);
                const bf16x8 vf1 = *reinterpret_cast<const bf16x8*>(
                    Vb + (32 + l31) * 128 + (coff ^ rswz0));
                o1 = __builtin_amdgcn_mfma_f32_32x32x16_bf16(vf1, pf.v, o1, 0, 0, 0);
            }
        }
        asm volatile("s_waitcnt vmcnt(0)" ::: "memory");
        gbar();
    }

    if (merged) {
        const int base = 2 * (qi - 2) + (qi == 7 ? 1 : 0);
        const int pb = bh * 14 + base + part;
        const int mrow = w * 32 + l31;
        if (hi == 0) {
            ml[pb * 512 + mrow] = mrun;
            ml[pb * 512 + 256 + mrow] = lrun;
        }
        unsigned short* dst = partO + (size_t)pb * 16384 + mrow * 64 + hi * 4;
#pragma unroll
        for (int qd = 0; qd < 4; ++qd) {
            uint2 pk0, pk1;
            pk0.x = cvtpk(o0[4 * qd + 0], o0[4 * qd + 1]);
            pk0.y = cvtpk(o0[4 * qd + 2], o0[4 * qd + 3]);
            pk1.x = cvtpk(o1[4 * qd + 0], o1[4 * qd + 1]);
            pk1.y = cvtpk(o1[4 * qd + 2], o1[4 * qd + 3]);
            *reinterpret_cast<uint2*>(dst + 8 * qd) = pk0;
            *reinterpret_cast<uint2*>(dst + 32 + 8 * qd) = pk1;
        }
    } else {
        const float inv = 1.0f / lrun;
        unsigned short* dst = attn_out + (size_t)(b * S_LEN + m) * D_MODEL + head * DHEAD + hi * 4;
#pragma unroll
        for (int qd = 0; qd < 4; ++qd) {
            uint2 pk0, pk1;
            pk0.x = cvtpk(o0[4 * qd + 0] * inv, o0[4 * qd + 1] * inv);
            pk0.y = cvtpk(o0[4 * qd + 2] * inv, o0[4 * qd + 3] * inv);
            pk1.x = cvtpk(o1[4 * qd + 0] * inv, o1[4 * qd + 1] * inv);
            pk1.y = cvtpk(o1[4 * qd + 2] * inv, o1[4 * qd + 3] * inv);
            *reinterpret_cast<uint2*>(dst + 8 * qd) = pk0;
            *reinterpret_cast<uint2*>(dst + 32 + 8 * qd) = pk1;
        }
    }
}

// ---------------- merge 2-3 KV-partials (qi 2..7) ----------------
__global__ __launch_bounds__(512) void merge3_kernel(const unsigned short* __restrict__ partO,
                                                     const float* __restrict__ ml,
                                                     unsigned short* __restrict__ attn_out) {
    const int blk = blockIdx.x;          // bh*6 + (qi-2)
    const int bh = blk / 6;
    const int qi = 2 + (blk - bh * 6);
    const int np = (qi >= 6) ? 3 : 2;
    const int base = 2 * (qi - 2) + (qi == 7 ? 1 : 0);
    const int pb = bh * 14 + base;
    const int b = bh >> 5, head = bh & 31;
    const int s0 = qi * QBLK;
    const int tid = threadIdx.x;
    const int row = tid >> 1, dh0 = (tid & 1) * 32;

    float m0 = ml[(pb + 0) * 512 + row], l0 = ml[(pb + 0) * 512 + 256 + row];
    float m1 = ml[(pb + 1) * 512 + row], l1 = ml[(pb + 1) * 512 + 256 + row];
    float m2 = -1e30f, l2 = 0.f;
    if (np == 3) { m2 = ml[(pb + 2) * 512 + row]; l2 = ml[(pb + 2) * 512 + 256 + row]; }
    const float M = fmaxf(fmaxf(m0, m1), m2);
    float w0 = __builtin_amdgcn_exp2f(m0 - M);
    float w1 = __builtin_amdgcn_exp2f(m1 - M);
    float w2 = (np == 3) ? __builtin_amdgcn_exp2f(m2 - M) : 0.f;
    const float inv = 1.0f / (l0 * w0 + l1 * w1 + l2 * w2);
    w0 *= inv; w1 *= inv; w2 *= inv;

    const uint4* p0 = reinterpret_cast<const uint4*>(partO + (size_t)(pb + 0) * 16384 + row * 64 + dh0);
    const uint4* p1 = reinterpret_cast<const uint4*>(partO + (size_t)(pb + 1) * 16384 + row * 64 + dh0);
    const uint4* p2 = reinterpret_cast<const uint4*>(partO + (size_t)(pb + 2) * 16384 + row * 64 + dh0);
    unsigned short* dst = attn_out + (size_t)(b * S_LEN + s0 + row) * D_MODEL + head * DHEAD + dh0;
#pragma unroll
    for (int c = 0; c < 4; ++c) {
        union { unsigned short u[8]; uint4 v; } ua, ub, uc, uo;
        ua.v = p0[c]; ub.v = p1[c];
        if (np == 3) uc.v = p2[c];
#pragma unroll
        for (int e = 0; e < 8; e += 2) {
            float x0 = bf2f(ua.u[e]) * w0 + bf2f(ub.u[e]) * w1;
            float x1 = bf2f(ua.u[e + 1]) * w0 + bf2f(ub.u[e + 1]) * w1;
            if (np == 3) {
                x0 += bf2f(uc.u[e]) * w2;
                x1 += bf2f(uc.u[e + 1]) * w2;
            }
            reinterpret_cast<uint32_t*>(uo.u)[e >> 1] = cvtpk(x0, x1);
        }
        reinterpret_cast<uint4*>(dst)[c] = uo.v;
    }
}

// ---------------- host launch ----------------
extern "C" void kernel_launch(void* const* d_in, const int* in_sizes, int n_in,
                              void* d_out, int out_size, void* d_ws, size_t ws_size,
                              hipStream_t stream) {
    const float* q     = (const float*)d_in[0];
    const float* k     = (const float*)d_in[1];
    const float* v     = (const float*)d_in[2];
    const float* w_q   = (const float*)d_in[4];
    const float* w_k   = (const float*)d_in[5];
    const float* w_v   = (const float*)d_in[6];
    const float* w_out = (const float*)d_in[7];

    char* ws = (char*)d_ws;
    size_t off = 0;
    auto alloc = [&](size_t n) { char* p = ws + off; off += (n + 255) & ~(size_t)255; return p; };
    unsigned short* qb   = (unsigned short*)alloc((size_t)M_TOK * D_MODEL * 2);  // ml after proj
    unsigned short* kb   = (unsigned short*)alloc((size_t)M_TOK * D_MODEL * 2);  // partO (w/ vb) after proj
    unsigned short* vb   = (unsigned short*)alloc((size_t)M_TOK * D_MODEL * 2);
    unsigned short* wqb  = (unsigned short*)alloc((size_t)D_MODEL * D_MODEL * 2);
    unsigned short* wkvb = (unsigned short*)alloc((size_t)2 * KV_DIM * D_MODEL * 2);
    unsigned short* wob  = (unsigned short*)alloc((size_t)D_MODEL * D_MODEL * 2);
    unsigned short* qpb  = (unsigned short*)alloc((size_t)M_TOK * D_MODEL * 2);
    unsigned short* kpb  = (unsigned short*)alloc((size_t)M_TOK * KV_DIM * 2);
    unsigned short* vtb  = (unsigned short*)alloc((size_t)M_TOK * KV_DIM * 2);
    unsigned short* aob  = (unsigned short*)alloc((size_t)M_TOK * D_MODEL * 2);

    cvt_all<<<dim3(17408), dim3(256), 0, stream>>>(q, k, v, w_q, w_k, w_v, w_out,
                                                   qb, kb, vb, wqb, wkvb, wob);

    gemm8p<<<dim3(192), dim3(512), 0, stream>>>(qb, kb, vb, wqb, wkvb, qpb, kpb, vtb);

    // attention: 1024 static items (4 blocks/CU); partO aliases kb+vb, ml aliases qb
    attn5_kernel<<<dim3(1024), dim3(512), 0, stream>>>(qpb, kpb, vtb, aob, kb, (float*)qb);
    merge3_kernel<<<dim3(384), dim3(512), 0, stream>>>(kb, (float*)qb, aob);

    gemm8o<<<dim3(256), dim3(512), 0, stream>>>(aob, wob, (float*)d_out);
}